// Round 12
// baseline (456.935 us; speedup 1.0000x reference)
//
#include <hip/hip_runtime.h>
#include <hip/hip_bf16.h>
#include <math.h>

#define B_N 8192
#define D_DIM 1024
#define NWORDS 128   // u64 words per mask row
#define NTILES 2080  // 64 diag + 2016 upper-triangle off-diag

using bf16 = __hip_bfloat16;
typedef float f32x4 __attribute__((ext_vector_type(4)));
typedef int i32x4 __attribute__((ext_vector_type(4)));
typedef int i32x8 __attribute__((ext_vector_type(8)));

// ws layout:
//   [0, 8MB)               : Xn fp8-e4m3 [8192][1024] (unit-norm rows, scale 1.0)
//   [8MB, 16MB)            : maskbits u64 [8192][128]
//   red = 16MB:
//     red + 0      .. 32KB : S[8192]  f32  (sum exp(sim-10), j != i)  [atomic, zeroed]
//     red + 32KB   .. 64KB : P[8192]  f32  (popcount of mask row)     [written by pack]
//     red + 64KB   + 4     : flag u32  (mask-dtype detection)         [atomic, zeroed]
//     red + 64KB+256 ..    : Mpart[2080] f32 (per-block sum mask*sim) [written by sim]

__global__ void detect_mask_kernel(const unsigned* __restrict__ m, unsigned* __restrict__ flag) {
    // Read first 1MB as u32. u8-bool mask at ~1% density -> ~3% of words >1.
    // i32 mask -> all words in {0,1} -> flag stays 0.
    unsigned c = 0;
    for (int i = blockIdx.x * blockDim.x + threadIdx.x; i < 262144;
         i += gridDim.x * blockDim.x) {
        c += (m[i] > 1u) ? 1u : 0u;
    }
    for (int s = 1; s < 64; s <<= 1) c += __shfl_xor(c, s, 64);
    if ((threadIdx.x & 63) == 0 && c) atomicAdd(flag, c);
}

// Fused: block b packs mask rows {2b, 2b+1} into bits (1 u64 word/thread,
// uint4 vector loads) AND L2-normalizes embedding rows {2b, 2b+1} -> fp8
// e4m3 (hardware cvt; unit-norm components |x|<=1 so uniform MX scale 1.0).
__global__ void norm_pack_kernel(const float* __restrict__ emb, unsigned char* __restrict__ xn8,
                                 const unsigned char* __restrict__ m8,
                                 const int* __restrict__ m32,
                                 const unsigned* __restrict__ flag,
                                 unsigned long long* __restrict__ bits,
                                 float* __restrict__ P) {
    const bool is_u8 = (*flag != 0u);
    int tid = threadIdx.x;
    // ---- pack: one u64 word per thread (64 mask elements) ----
    size_t w = (size_t)blockIdx.x * 256 + tid;
    unsigned long long word = 0;
    if (is_u8) {
        const uint4* src = (const uint4*)(m8 + w * 64);
#pragma unroll
        for (int q = 0; q < 4; ++q) {
            uint4 v = src[q];
            unsigned cs[4] = {v.x, v.y, v.z, v.w};
#pragma unroll
            for (int c = 0; c < 4; ++c) {
                unsigned u = ((cs[c] & 0x7F7F7F7Fu) + 0x7F7F7F7Fu) | cs[c];
                u &= 0x80808080u;
                unsigned nib = ((u >> 7) & 1u) | ((u >> 14) & 2u) | ((u >> 21) & 4u) | ((u >> 28) & 8u);
                word |= (unsigned long long)nib << ((q * 4 + c) * 4);
            }
        }
    } else {
        const uint4* src = (const uint4*)(m32 + w * 64);
#pragma unroll
        for (int q = 0; q < 16; ++q) {
            uint4 v = src[q];
            unsigned nib = (unsigned)(v.x != 0) | ((unsigned)(v.y != 0) << 1) |
                           ((unsigned)(v.z != 0) << 2) | ((unsigned)(v.w != 0) << 3);
            word |= (unsigned long long)nib << (q * 4);
        }
    }
    bits[w] = word;
    float pc = (float)__popcll(word);
    for (int s = 1; s < 64; s <<= 1) pc += __shfl_xor(pc, s, 64);
    __shared__ float wsum[4];
    if ((tid & 63) == 0) wsum[tid >> 6] = pc;
    __syncthreads();
    if (tid == 0)   P[blockIdx.x * 2]     = wsum[0] + wsum[1];
    if (tid == 128) P[blockIdx.x * 2 + 1] = wsum[2] + wsum[3];

    // ---- normalize rows 2b, 2b+1 (256 threads x float4 each) -> fp8 ----
    __shared__ float wss[4];
#pragma unroll
    for (int rr = 0; rr < 2; ++rr) {
        int row = blockIdx.x * 2 + rr;
        const float4* src = (const float4*)(emb + (size_t)row * D_DIM);
        float4 v = src[tid];
        float ss = v.x * v.x + v.y * v.y + v.z * v.z + v.w * v.w;
        for (int s = 1; s < 64; s <<= 1) ss += __shfl_xor(ss, s, 64);
        __syncthreads();  // protect wss reuse across rr
        if ((tid & 63) == 0) wss[tid >> 6] = ss;
        __syncthreads();
        float tot = wss[0] + wss[1] + wss[2] + wss[3];
        float scale = 1.0f / fmaxf(sqrtf(tot), 1e-12f);
        unsigned pk = __builtin_amdgcn_cvt_pk_fp8_f32(v.x * scale, v.y * scale, 0, false);
        pk = __builtin_amdgcn_cvt_pk_fp8_f32(v.z * scale, v.w * scale, (int)pk, true);
        *reinterpret_cast<unsigned*>(xn8 + (size_t)row * D_DIM + tid * 4) = pk;
    }
}

// Upper-triangle tiling: 64 diag + 2016 off-diag = 2080 blocks.
// 128x128 tile, 4 waves (2x2), per-wave 64x64 = 4x4 frags. R7's proven
// 2-barrier K-loop + XOR swizzle, but fp8-MX core: BK=128 (128B/row slice,
// byte-identical staging geometry to the bf16 version), 8 K-steps, one
// mfma_scale_f32_16x16x128_f8f6f4 per frag pair (cbsz=blgp=0 -> e4m3,
// uniform e8m0 scale 127 = 1.0). Each lane's 32 consecutive k-bytes load as
// two swizzled ds_read_b128 (chunks c0, c0^16).
__global__ __launch_bounds__(256, 2) void sim_kernel(
    const unsigned char* __restrict__ xn8,
    const unsigned long long* __restrict__ mbits,
    float* __restrict__ S, float* __restrict__ Mpart)
{
    __shared__ __align__(16) unsigned char Abuf[128 * 128];  // 16KB
    __shared__ __align__(16) unsigned char Bbuf[128 * 128];  // 16KB
    __shared__ float Mred[4];

    // XCD-aware bijective swizzle (2080 % 8 == 0 -> 260 per XCD)
    int b0 = blockIdx.x;
    int tile = (b0 & 7) * 260 + (b0 >> 3);
    int by, bx;
    bool isdiag;
    if (tile < 64) {
        by = bx = tile;
        isdiag = true;
    } else {
        int j = tile - 64;  // [0, 2016)
        int p = (int)((sqrt((double)(8 * j + 1)) + 1.0) * 0.5);
        while (p * (p - 1) / 2 > j) --p;
        while ((p + 1) * p / 2 <= j) ++p;
        int q = j - p * (p - 1) / 2;
        by = q; bx = p;  // by < bx
        isdiag = false;
    }

    int t = threadIdx.x;
    int w = t >> 6, lane = t & 63;
    int wm = w >> 1, wn = w & 1;
    int l15 = lane & 15, lg = lane >> 4;

    f32x4 acc[4][4];
#pragma unroll
    for (int i = 0; i < 4; i++)
#pragma unroll
        for (int j = 0; j < 4; j++) acc[i][j] = {0.f, 0.f, 0.f, 0.f};

    int arow0 = by << 7;
    int brow0 = bx << 7;

    // Staging: e = i*256 + w*64 + lane (16B units); row = e>>3, dest chunk =
    // lane&7 (linear), source chunk pre-swizzled (lane&7)^(lane>>3).
    int ebase0 = w * 64;
    int csrc16 = (((lane & 7) ^ (lane >> 3)) << 4);  // byte offset in 128B slice
    int rlane = (w << 3) + (lane >> 3);
    int xr = l15 & 7;

    for (int kt = 0; kt < 8; ++kt) {
#pragma unroll
        for (int i = 0; i < 4; ++i) {
            int ebase = i * 256 + ebase0;    // wave-uniform LDS 16B-slot base
            int r = i * 32 + rlane;
            const unsigned char* gA = xn8 + (size_t)(arow0 + r) * D_DIM + kt * 128 + csrc16;
            const unsigned char* gB = xn8 + (size_t)(brow0 + r) * D_DIM + kt * 128 + csrc16;
            char* lA = (char*)Abuf + (size_t)ebase * 16;
            char* lB = (char*)Bbuf + (size_t)ebase * 16;
            __builtin_amdgcn_global_load_lds((const __attribute__((address_space(1))) void*)gA,
                                             (__attribute__((address_space(3))) void*)lA, 16, 0, 0);
            __builtin_amdgcn_global_load_lds((const __attribute__((address_space(1))) void*)gB,
                                             (__attribute__((address_space(3))) void*)lB, 16, 0, 0);
        }
        __syncthreads();

        i32x8 a[4], b[4];
        {
            int c0 = (((lg << 1) ^ xr) << 4);   // swizzled byte offset of chunk 2*lg
            int c1 = c0 ^ 16;                   // chunk 2*lg+1 (XOR commutes: ^1 on index)
#pragma unroll
            for (int f = 0; f < 4; ++f) {
                int rowA = (wm * 64 + f * 16 + l15) << 7;
                int rowB = (wn * 64 + f * 16 + l15) << 7;
                i32x4 alo = *reinterpret_cast<const i32x4*>(Abuf + rowA + c0);
                i32x4 ahi = *reinterpret_cast<const i32x4*>(Abuf + rowA + c1);
                i32x4 blo = *reinterpret_cast<const i32x4*>(Bbuf + rowB + c0);
                i32x4 bhi = *reinterpret_cast<const i32x4*>(Bbuf + rowB + c1);
                a[f][0] = alo[0]; a[f][1] = alo[1]; a[f][2] = alo[2]; a[f][3] = alo[3];
                a[f][4] = ahi[0]; a[f][5] = ahi[1]; a[f][6] = ahi[2]; a[f][7] = ahi[3];
                b[f][0] = blo[0]; b[f][1] = blo[1]; b[f][2] = blo[2]; b[f][3] = blo[3];
                b[f][4] = bhi[0]; b[f][5] = bhi[1]; b[f][6] = bhi[2]; b[f][7] = bhi[3];
            }
        }
#pragma unroll
        for (int fm = 0; fm < 4; ++fm)
#pragma unroll
            for (int fn = 0; fn < 4; ++fn)
                acc[fm][fn] = __builtin_amdgcn_mfma_scale_f32_16x16x128_f8f6f4(
                    a[fm], b[fn], acc[fm][fn], 0, 0,
                    0, 0x7F7F7F7F, 0, 0x7F7F7F7F);  // e4m3/e4m3, scale 2^0
        __syncthreads();
    }

    // ---- Epilogue ----
    // C/D layout: col = l15, row = lg*4 + reg (within 16x16 frag).
    float colE[4] = {0.f, 0.f, 0.f, 0.f};
    unsigned long long wcol[4] = {0, 0, 0, 0};
    if (!isdiag) {
#pragma unroll
        for (int fn = 0; fn < 4; ++fn) {
            int gc = brow0 + wn * 64 + fn * 16 + l15;
            wcol[fn] = mbits[(size_t)gc * NWORDS + by * 2 + wm];
        }
    }

    float Mloc = 0.f;
#pragma unroll
    for (int fm = 0; fm < 4; ++fm) {
#pragma unroll
        for (int reg = 0; reg < 4; ++reg) {
            int lr = fm * 16 + lg * 4 + reg;          // row within wave tile
            int gr = arow0 + wm * 64 + lr;
            unsigned long long wrow = mbits[(size_t)gr * NWORDS + bx * 2 + wn];
            float E = 0.f;
#pragma unroll
            for (int fn = 0; fn < 4; ++fn) {
                int gc = brow0 + wn * 64 + fn * 16 + l15;
                float sim = acc[fm][fn][reg] * 10.0f;
                float e = __expf(sim - 10.0f);
                if (isdiag && gr == gc) e = 0.f;
                E += e;
                if ((wrow >> (fn * 16 + l15)) & 1ull) Mloc += sim;
                if (!isdiag) {
                    colE[fn] += e;
                    if ((wcol[fn] >> lr) & 1ull) Mloc += sim;
                }
            }
            E += __shfl_xor(E, 1, 64);
            E += __shfl_xor(E, 2, 64);
            E += __shfl_xor(E, 4, 64);
            E += __shfl_xor(E, 8, 64);
            if (l15 == 0) atomicAdd(&S[gr], E);
        }
    }

    if (!isdiag) {
#pragma unroll
        for (int fn = 0; fn < 4; ++fn) {
            float E = colE[fn];
            E += __shfl_xor(E, 16, 64);
            E += __shfl_xor(E, 32, 64);
            if (lg == 0) atomicAdd(&S[brow0 + wn * 64 + fn * 16 + l15], E);
        }
    }

    for (int s = 1; s < 64; s <<= 1) Mloc += __shfl_xor(Mloc, s, 64);
    if (lane == 0) Mred[w] = Mloc;
    __syncthreads();
    if (t == 0) Mpart[b0] = Mred[0] + Mred[1] + Mred[2] + Mred[3];
}

__global__ void finalize_kernel(const float* __restrict__ S, const float* __restrict__ P,
                                const float* __restrict__ Mpart, float* __restrict__ out) {
    int t = threadIdx.x;  // 1024
    double a = 0.0;
    for (int i = t; i < B_N; i += 1024) {
        float lse = 10.0f + logf(S[i]);
        a += (double)P[i] * (double)lse;
    }
    for (int i = t; i < NTILES; i += 1024) a -= (double)Mpart[i];
    for (int s = 1; s < 64; s <<= 1) a += __shfl_xor(a, s, 64);
    __shared__ double sh[16];
    if ((t & 63) == 0) sh[t >> 6] = a;
    __syncthreads();
    if (t == 0) {
        double tot = 0.0;
        for (int i = 0; i < 16; ++i) tot += sh[i];
        out[0] = (float)(tot / (double)B_N);
    }
}

extern "C" void kernel_launch(void* const* d_in, const int* in_sizes, int n_in,
                              void* d_out, int out_size, void* d_ws, size_t ws_size,
                              hipStream_t stream) {
    const float* emb = (const float*)d_in[0];
    const void* mask = d_in[1];
    char* ws = (char*)d_ws;
    unsigned char* xn8 = (unsigned char*)ws;
    const size_t XN_BYTES = (size_t)B_N * D_DIM;                  // 8MB (fp8)
    unsigned long long* mbits = (unsigned long long*)(ws + XN_BYTES);
    const size_t MB_BYTES = (size_t)B_N * NWORDS * 8;             // 8MB
    char* red = ws + XN_BYTES + MB_BYTES;
    float* S = (float*)red;
    float* P = (float*)(red + 32768);
    unsigned* flag = (unsigned*)(red + 65536 + 4);
    float* Mpart = (float*)(red + 65536 + 256);

    hipMemsetAsync(red, 0, 65536 + 16, stream);
    detect_mask_kernel<<<64, 256, 0, stream>>>((const unsigned*)mask, flag);
    norm_pack_kernel<<<4096, 256, 0, stream>>>(emb, xn8, (const unsigned char*)mask,
                                               (const int*)mask, flag, mbits, P);
    sim_kernel<<<NTILES, 256, 0, stream>>>(xn8, mbits, S, Mpart);
    finalize_kernel<<<1, 1024, 0, stream>>>(S, P, Mpart, (float*)d_out);
}

// Round 13
// 203.952 us; speedup vs baseline: 2.2404x; 2.2404x over previous
//
#include <hip/hip_runtime.h>
#include <hip/hip_bf16.h>
#include <math.h>

#define B_N 8192
#define D_DIM 1024
#define NWORDS 128   // u64 words per mask row
#define NTILES 2080  // 64 diag + 2016 upper-triangle off-diag

using bf16 = __hip_bfloat16;
typedef float f32x4 __attribute__((ext_vector_type(4)));
typedef __bf16 bf16x8 __attribute__((ext_vector_type(8)));

// ws layout:
//   [0, 16MB)                : Xn bf16 [8192][1024]
//   [16MB, 24MB)             : maskbits u64 [8192][128]
//   red = 24MB:
//     red + 0      .. 32KB   : S[8192]  f32  (sum exp(sim-10), j != i)  [atomic, zeroed]
//     red + 32KB   .. 64KB   : P[8192]  f32  (popcount of mask row)     [written by pack]
//     red + 64KB   + 4       : flag u32  (mask-dtype detection)         [atomic, zeroed]
//     red + 64KB+256 ..      : Mpart[2080] f32 (per-block sum mask*sim) [written by sim]

__global__ void detect_mask_kernel(const unsigned* __restrict__ m, unsigned* __restrict__ flag) {
    unsigned c = 0;
    for (int i = blockIdx.x * blockDim.x + threadIdx.x; i < 262144;
         i += gridDim.x * blockDim.x) {
        c += (m[i] > 1u) ? 1u : 0u;
    }
    for (int s = 1; s < 64; s <<= 1) c += __shfl_xor(c, s, 64);
    if ((threadIdx.x & 63) == 0 && c) atomicAdd(flag, c);
}

// Fused: block b packs mask rows {2b, 2b+1} into bits (1 u64 word/thread,
// uint4 vector loads) AND L2-normalizes embedding rows {2b, 2b+1} -> bf16.
__global__ void norm_pack_kernel(const float* __restrict__ emb, bf16* __restrict__ xn,
                                 const unsigned char* __restrict__ m8,
                                 const int* __restrict__ m32,
                                 const unsigned* __restrict__ flag,
                                 unsigned long long* __restrict__ bits,
                                 float* __restrict__ P) {
    const bool is_u8 = (*flag != 0u);
    int tid = threadIdx.x;
    size_t w = (size_t)blockIdx.x * 256 + tid;
    unsigned long long word = 0;
    if (is_u8) {
        const uint4* src = (const uint4*)(m8 + w * 64);
#pragma unroll
        for (int q = 0; q < 4; ++q) {
            uint4 v = src[q];
            unsigned cs[4] = {v.x, v.y, v.z, v.w};
#pragma unroll
            for (int c = 0; c < 4; ++c) {
                unsigned u = ((cs[c] & 0x7F7F7F7Fu) + 0x7F7F7F7Fu) | cs[c];
                u &= 0x80808080u;
                unsigned nib = ((u >> 7) & 1u) | ((u >> 14) & 2u) | ((u >> 21) & 4u) | ((u >> 28) & 8u);
                word |= (unsigned long long)nib << ((q * 4 + c) * 4);
            }
        }
    } else {
        const uint4* src = (const uint4*)(m32 + w * 64);
#pragma unroll
        for (int q = 0; q < 16; ++q) {
            uint4 v = src[q];
            unsigned nib = (unsigned)(v.x != 0) | ((unsigned)(v.y != 0) << 1) |
                           ((unsigned)(v.z != 0) << 2) | ((unsigned)(v.w != 0) << 3);
            word |= (unsigned long long)nib << (q * 4);
        }
    }
    bits[w] = word;
    float pc = (float)__popcll(word);
    for (int s = 1; s < 64; s <<= 1) pc += __shfl_xor(pc, s, 64);
    __shared__ float wsum[4];
    if ((tid & 63) == 0) wsum[tid >> 6] = pc;
    __syncthreads();
    if (tid == 0)   P[blockIdx.x * 2]     = wsum[0] + wsum[1];
    if (tid == 128) P[blockIdx.x * 2 + 1] = wsum[2] + wsum[3];

    __shared__ float wss[4];
#pragma unroll
    for (int rr = 0; rr < 2; ++rr) {
        int row = blockIdx.x * 2 + rr;
        const float4* src = (const float4*)(emb + (size_t)row * D_DIM);
        float4 v = src[tid];
        float ss = v.x * v.x + v.y * v.y + v.z * v.z + v.w * v.w;
        for (int s = 1; s < 64; s <<= 1) ss += __shfl_xor(ss, s, 64);
        __syncthreads();
        if ((tid & 63) == 0) wss[tid >> 6] = ss;
        __syncthreads();
        float tot = wss[0] + wss[1] + wss[2] + wss[3];
        float scale = 1.0f / fmaxf(sqrtf(tot), 1e-12f);
        ushort4 o;
        o.x = __builtin_bit_cast(unsigned short, __float2bfloat16(v.x * scale));
        o.y = __builtin_bit_cast(unsigned short, __float2bfloat16(v.y * scale));
        o.z = __builtin_bit_cast(unsigned short, __float2bfloat16(v.z * scale));
        o.w = __builtin_bit_cast(unsigned short, __float2bfloat16(v.w * scale));
        *reinterpret_cast<ushort4*>(xn + (size_t)row * D_DIM + tid * 4) = o;
    }
}

// Upper-triangle tiling: 64 diag + 2016 off-diag = 2080 blocks.
// 128x128 tile, 4 waves (2x2), per-wave 64x64 = 4x4 frags of 16x16x32.
// K-loop: BK=32, 3-bank LDS rotation (48KB -> 3 blocks/CU) with counted
// vmcnt: iter t computes bank t%3 while staging tile t+2 into bank (t+2)%3;
// iter ends s_waitcnt vmcnt(4) (previous tile's 4 loads landed, this iter's
// 4 in flight with a full iteration of cover) + raw barrier + sched_barrier.
// (R8's 148KB variant proved the mechanism but died of 1-block/CU occupancy;
// this keeps 3 blocks/CU.) Swizzle: chunk ^= (row>>2)&3 on both sides
// (pre-swizzled global source, linear gload_lds dest) -> 2-way aliasing, free.
__global__ __launch_bounds__(256, 3) void sim_kernel(
    const bf16* __restrict__ xn,
    const unsigned long long* __restrict__ mbits,
    float* __restrict__ S, float* __restrict__ Mpart)
{
    __shared__ __align__(16) bf16 SL[3 * 8192];  // 3 banks x (A 4096 + B 4096) = 48KB
    __shared__ float Mred[4];

    // XCD-aware bijective swizzle (2080 % 8 == 0 -> 260 per XCD)
    int b0 = blockIdx.x;
    int tile = (b0 & 7) * 260 + (b0 >> 3);
    int by, bx;
    bool isdiag;
    if (tile < 64) {
        by = bx = tile;
        isdiag = true;
    } else {
        int j = tile - 64;  // [0, 2016)
        int p = (int)((sqrt((double)(8 * j + 1)) + 1.0) * 0.5);
        while (p * (p - 1) / 2 > j) --p;
        while ((p + 1) * p / 2 <= j) ++p;
        int q = j - p * (p - 1) / 2;
        by = q; bx = p;  // by < bx
        isdiag = false;
    }

    int t = threadIdx.x;
    int w = t >> 6, lane = t & 63;
    int wm = w >> 1, wn = w & 1;
    int l15 = lane & 15, lg = lane >> 4;

    f32x4 acc[4][4];
#pragma unroll
    for (int i = 0; i < 4; i++)
#pragma unroll
        for (int j = 0; j < 4; j++) acc[i][j] = {0.f, 0.f, 0.f, 0.f};

    int arow0 = by << 7;
    int brow0 = bx << 7;

    // Staging: per matrix per tile: 128 rows x 32 bf16 (64B = 4 chunks of 16B),
    // 2 rounds x 256 threads x 16B. slot = i*256 + w*64 + lane; row = slot>>2
    // = i*64 + w*16 + (lane>>2); dest chunk = lane&3 (linear); source chunk =
    // (lane&3) ^ ((row>>2)&3) = (lane&3) ^ ((lane>>4)&3).
    int csrc = ((lane & 3) ^ ((lane >> 4) & 3)) << 3;  // element offset in row slice
    int rA = w * 16 + (lane >> 2);                     // + i*64 = row within tile
    // Read side: row = *64 + f*16 + l15; chunk = lg ^ ((row>>2)&3) = lg ^ ((l15>>2)&3)
    int ca = (lg ^ ((l15 >> 2) & 3)) << 3;             // element offset

#define STAGE(bk, kt)                                                                       \
    do {                                                                                    \
        bf16* Ad = SL + (bk) * 8192;                                                        \
        bf16* Bd = Ad + 4096;                                                               \
        _Pragma("unroll") for (int i = 0; i < 2; ++i) {                                     \
            const bf16* gA = xn + (size_t)(arow0 + i * 64 + rA) * D_DIM + (kt) * 32 + csrc; \
            const bf16* gB = xn + (size_t)(brow0 + i * 64 + rA) * D_DIM + (kt) * 32 + csrc; \
            char* lA = (char*)Ad + (size_t)(i * 256 + w * 64) * 16;                         \
            char* lB = (char*)Bd + (size_t)(i * 256 + w * 64) * 16;                         \
            __builtin_amdgcn_global_load_lds((const __attribute__((address_space(1))) void*)gA, \
                                             (__attribute__((address_space(3))) void*)lA, 16, 0, 0); \
            __builtin_amdgcn_global_load_lds((const __attribute__((address_space(1))) void*)gB, \
                                             (__attribute__((address_space(3))) void*)lB, 16, 0, 0); \
        }                                                                                   \
    } while (0)

    // prologue: tiles 0,1 in flight; wait tile 0 (4 newest may fly)
    STAGE(0, 0);
    STAGE(1, 1);
    asm volatile("s_waitcnt vmcnt(4)" ::: "memory");
    __builtin_amdgcn_s_barrier();
    __builtin_amdgcn_sched_barrier(0);

    int cur = 0, stg = 2;
    for (int kt = 0; kt < 32; ++kt) {
        bf16* Ab = SL + cur * 8192;
        bf16* Bb = Ab + 4096;
        if (kt < 30) STAGE(stg, kt + 2);

        bf16x8 a[4], b[4];
#pragma unroll
        for (int f = 0; f < 4; ++f) {
            a[f] = *reinterpret_cast<const bf16x8*>(Ab + (wm * 64 + f * 16 + l15) * 32 + ca);
            b[f] = *reinterpret_cast<const bf16x8*>(Bb + (wn * 64 + f * 16 + l15) * 32 + ca);
        }
#pragma unroll
        for (int fm = 0; fm < 4; ++fm)
#pragma unroll
            for (int fn = 0; fn < 4; ++fn)
                acc[fm][fn] = __builtin_amdgcn_mfma_f32_16x16x32_bf16(a[fm], b[fn], acc[fm][fn], 0, 0, 0);

        if (kt < 31) {
            if (kt < 30) asm volatile("s_waitcnt vmcnt(4)" ::: "memory");
            else         asm volatile("s_waitcnt vmcnt(0)" ::: "memory");
            __builtin_amdgcn_s_barrier();
            __builtin_amdgcn_sched_barrier(0);
        }
        cur = (cur == 2) ? 0 : cur + 1;
        stg = (stg == 2) ? 0 : stg + 1;
    }
#undef STAGE

    // ---- Epilogue (identical to R11/verified) ----
    // C/D layout: col = l15, row = lg*4 + reg (within 16x16 frag).
    float colE[4] = {0.f, 0.f, 0.f, 0.f};
    unsigned long long wcol[4] = {0, 0, 0, 0};
    if (!isdiag) {
#pragma unroll
        for (int fn = 0; fn < 4; ++fn) {
            int gc = brow0 + wn * 64 + fn * 16 + l15;
            wcol[fn] = mbits[(size_t)gc * NWORDS + by * 2 + wm];
        }
    }

    float Mloc = 0.f;
#pragma unroll
    for (int fm = 0; fm < 4; ++fm) {
#pragma unroll
        for (int reg = 0; reg < 4; ++reg) {
            int lr = fm * 16 + lg * 4 + reg;          // row within wave tile
            int gr = arow0 + wm * 64 + lr;
            unsigned long long wrow = mbits[(size_t)gr * NWORDS + bx * 2 + wn];
            float E = 0.f;
#pragma unroll
            for (int fn = 0; fn < 4; ++fn) {
                int gc = brow0 + wn * 64 + fn * 16 + l15;
                float sim = acc[fm][fn][reg] * 10.0f;
                float e = __expf(sim - 10.0f);
                if (isdiag && gr == gc) e = 0.f;
                E += e;
                if ((wrow >> (fn * 16 + l15)) & 1ull) Mloc += sim;
                if (!isdiag) {
                    colE[fn] += e;
                    if ((wcol[fn] >> lr) & 1ull) Mloc += sim;
                }
            }
            E += __shfl_xor(E, 1, 64);
            E += __shfl_xor(E, 2, 64);
            E += __shfl_xor(E, 4, 64);
            E += __shfl_xor(E, 8, 64);
            if (l15 == 0) atomicAdd(&S[gr], E);
        }
    }

    if (!isdiag) {
#pragma unroll
        for (int fn = 0; fn < 4; ++fn) {
            float E = colE[fn];
            E += __shfl_xor(E, 16, 64);
            E += __shfl_xor(E, 32, 64);
            if (lg == 0) atomicAdd(&S[brow0 + wn * 64 + fn * 16 + l15], E);
        }
    }

    for (int s = 1; s < 64; s <<= 1) Mloc += __shfl_xor(Mloc, s, 64);
    if (lane == 0) Mred[w] = Mloc;
    __syncthreads();
    if (t == 0) Mpart[b0] = Mred[0] + Mred[1] + Mred[2] + Mred[3];
}

__global__ void finalize_kernel(const float* __restrict__ S, const float* __restrict__ P,
                                const float* __restrict__ Mpart, float* __restrict__ out) {
    int t = threadIdx.x;  // 1024
    double a = 0.0;
    for (int i = t; i < B_N; i += 1024) {
        float lse = 10.0f + logf(S[i]);
        a += (double)P[i] * (double)lse;
    }
    for (int i = t; i < NTILES; i += 1024) a -= (double)Mpart[i];
    for (int s = 1; s < 64; s <<= 1) a += __shfl_xor(a, s, 64);
    __shared__ double sh[16];
    if ((t & 63) == 0) sh[t >> 6] = a;
    __syncthreads();
    if (t == 0) {
        double tot = 0.0;
        for (int i = 0; i < 16; ++i) tot += sh[i];
        out[0] = (float)(tot / (double)B_N);
    }
}

extern "C" void kernel_launch(void* const* d_in, const int* in_sizes, int n_in,
                              void* d_out, int out_size, void* d_ws, size_t ws_size,
                              hipStream_t stream) {
    const float* emb = (const float*)d_in[0];
    const void* mask = d_in[1];
    char* ws = (char*)d_ws;
    bf16* xn = (bf16*)ws;
    const size_t XN_BYTES = (size_t)B_N * D_DIM * 2;              // 16MB
    unsigned long long* mbits = (unsigned long long*)(ws + XN_BYTES);
    const size_t MB_BYTES = (size_t)B_N * NWORDS * 8;             // 8MB
    char* red = ws + XN_BYTES + MB_BYTES;
    float* S = (float*)red;
    float* P = (float*)(red + 32768);
    unsigned* flag = (unsigned*)(red + 65536 + 4);
    float* Mpart = (float*)(red + 65536 + 256);

    hipMemsetAsync(red, 0, 65536 + 16, stream);
    detect_mask_kernel<<<64, 256, 0, stream>>>((const unsigned*)mask, flag);
    norm_pack_kernel<<<4096, 256, 0, stream>>>(emb, xn, (const unsigned char*)mask,
                                               (const int*)mask, flag, mbits, P);
    sim_kernel<<<NTILES, 256, 0, stream>>>(xn, mbits, S, Mpart);
    finalize_kernel<<<1, 1024, 0, stream>>>(S, P, Mpart, (float*)d_out);
}